// Round 1
// baseline (68.026 us; speedup 1.0000x reference)
//
#include <hip/hip_runtime.h>

// TotalVariation over [32,8,3,256,256] f32 = 768 images of 256x256.
// tv = (sum|dh+eps| + sum|dw+eps|) / N, N = 50331648.

#define EPS 1e-6f

static constexpr int ROW  = 256;          // last-dim length (H)
static constexpr int IMG  = 256 * 256;    // elems per image
static constexpr long long NTOT = 32LL * 8 * 3 * 256 * 256;  // 50,331,648
static constexpr int NV   = (int)(NTOT / 4);                 // float4 count

__global__ void __launch_bounds__(256)
tv_reduce_kernel(const float* __restrict__ x, double* __restrict__ ws, int nv) {
    const int stride = gridDim.x * blockDim.x;
    float acc = 0.0f;
    for (int v = blockIdx.x * blockDim.x + threadIdx.x; v < nv; v += stride) {
        const int i = v << 2;                       // element index, < 2^26
        const float4 a = *reinterpret_cast<const float4*>(x + i);
        const int r = (i >> 8) & 255;               // row within image
        const int c = i & 255;                      // col within image (mult of 4)

        // horizontal diffs fully inside this float4
        acc += fabsf(a.y - a.x + EPS);
        acc += fabsf(a.z - a.y + EPS);
        acc += fabsf(a.w - a.z + EPS);
        // 4th horizontal diff crosses into next float4 (skip at row end c==252)
        if (c < 252) {
            const float nx = x[i + 4];
            acc += fabsf(nx - a.w + EPS);
        }
        // vertical diffs vs row below (wave-uniform branch; skip last row)
        if (r < 255) {
            const float4 b = *reinterpret_cast<const float4*>(x + i + ROW);
            acc += fabsf(b.x - a.x + EPS);
            acc += fabsf(b.y - a.y + EPS);
            acc += fabsf(b.z - a.z + EPS);
            acc += fabsf(b.w - a.w + EPS);
        }
    }

    // wave (64-lane) reduction
    #pragma unroll
    for (int off = 32; off > 0; off >>= 1)
        acc += __shfl_down(acc, off, 64);

    __shared__ double sdata[4];                     // 256 threads = 4 waves
    const int wid  = threadIdx.x >> 6;
    const int lane = threadIdx.x & 63;
    if (lane == 0) sdata[wid] = (double)acc;
    __syncthreads();
    if (threadIdx.x == 0) {
        const double s = sdata[0] + sdata[1] + sdata[2] + sdata[3];
        atomicAdd(ws, s);
    }
}

__global__ void tv_finalize_kernel(const double* __restrict__ ws,
                                   float* __restrict__ out) {
    out[0] = (float)(ws[0] / (double)NTOT);
}

extern "C" void kernel_launch(void* const* d_in, const int* in_sizes, int n_in,
                              void* d_out, int out_size, void* d_ws, size_t ws_size,
                              hipStream_t stream) {
    const float* x   = (const float*)d_in[0];
    float*       out = (float*)d_out;
    double*      ws  = (double*)d_ws;

    // zero the accumulator each call (graph-capture-safe)
    hipMemsetAsync(ws, 0, sizeof(double), stream);

    const int blocks = 2048;     // 256 CUs * 8 blocks; ~24 float4 iters/thread
    tv_reduce_kernel<<<blocks, 256, 0, stream>>>(x, ws, NV);
    tv_finalize_kernel<<<1, 1, 0, stream>>>(ws, out);
}

// Round 2
// 53.962 us; speedup vs baseline: 1.2606x; 1.2606x over previous
//
#include <hip/hip_runtime.h>

// TotalVariation over [32,8,3,256,256] f32 = 768 images of 256x256.
// tv = (sum|dh+eps| + sum|dw+eps|) / N, N = 50331648.
//
// Strip-walk design: each 64-lane wave owns a 32-row strip of one image.
// A row is exactly 64 float4s -> one wave-wide coalesced 1KB load.
// Walking down rows keeps the previous row in registers, so vertical
// diffs need no duplicate loads; horizontal cross-diff uses __shfl_down.

#define EPS 1e-6f

static constexpr long long NTOT = 32LL * 8 * 3 * 256 * 256;  // 50,331,648
static constexpr int R          = 32;                        // rows per strip
static constexpr int STRIPS     = 768 * (256 / R);           // 6144
static constexpr int BLOCKS     = STRIPS / 4;                // 4 waves/block

__global__ void __launch_bounds__(256)
tv_strip_kernel(const float* __restrict__ x, double* __restrict__ ws) {
    const int wid   = threadIdx.x >> 6;
    const int lane  = threadIdx.x & 63;
    const int strip = (blockIdx.x << 2) + wid;       // 0 .. 6143
    const int img   = strip >> 3;                    // 8 strips per image
    const int r0    = (strip & 7) << 5;              // r0 = (strip%8)*32

    const float* p = x + (size_t)img * 65536 + (size_t)r0 * 256 + lane * 4;

    float acc = 0.0f;
    float4 a = *reinterpret_cast<const float4*>(p);

    #pragma unroll 4
    for (int k = 0; k < R; ++k) {
        // horizontal diffs inside this float4
        acc += fabsf(a.y - a.x + EPS);
        acc += fabsf(a.z - a.y + EPS);
        acc += fabsf(a.w - a.z + EPS);
        // cross-float4 horizontal diff: neighbor lane's first element.
        // lane 63 is the row end (c==252) -> masked out.
        const float nx = __shfl_down(a.x, 1, 64);
        if (lane < 63) acc += fabsf(nx - a.w + EPS);

        // vertical diff vs next row (wave-uniform; r==255 only at the
        // last iteration of the last strip of an image)
        if (r0 + k < 255) {
            const float4 b = *reinterpret_cast<const float4*>(p + (k + 1) * 256);
            acc += fabsf(b.x - a.x + EPS);
            acc += fabsf(b.y - a.y + EPS);
            acc += fabsf(b.z - a.z + EPS);
            acc += fabsf(b.w - a.w + EPS);
            a = b;
        }
    }

    // wave reduction
    #pragma unroll
    for (int off = 32; off > 0; off >>= 1)
        acc += __shfl_down(acc, off, 64);

    __shared__ double sdata[4];
    if (lane == 0) sdata[wid] = (double)acc;
    __syncthreads();
    if (threadIdx.x == 0) {
        const double s = sdata[0] + sdata[1] + sdata[2] + sdata[3];
        atomicAdd(ws, s);
    }
}

__global__ void tv_finalize_kernel(const double* __restrict__ ws,
                                   float* __restrict__ out) {
    out[0] = (float)(ws[0] / (double)NTOT);
}

extern "C" void kernel_launch(void* const* d_in, const int* in_sizes, int n_in,
                              void* d_out, int out_size, void* d_ws, size_t ws_size,
                              hipStream_t stream) {
    const float* x   = (const float*)d_in[0];
    float*       out = (float*)d_out;
    double*      ws  = (double*)d_ws;

    hipMemsetAsync(ws, 0, sizeof(double), stream);
    tv_strip_kernel<<<BLOCKS, 256, 0, stream>>>(x, ws);
    tv_finalize_kernel<<<1, 1, 0, stream>>>(ws, out);
}

// Round 3
// 38.720 us; speedup vs baseline: 1.7569x; 1.3937x over previous
//
#include <hip/hip_runtime.h>

// TotalVariation over [32,8,3,256,256] f32 = 768 images of 256x256.
// tv = (sum|dh+eps| + sum|dw+eps|) / N, N = 50331648.
//
// Each 64-lane wave owns a 32-row strip of one image; a row is exactly
// 64 float4s -> one wave-wide coalesced 1KB load per row. Walking down
// keeps the previous row in registers (vertical diffs need no re-load);
// the cross-float4 horizontal diff comes from __shfl_down. The inner
// loop is branch-free so loads pipeline 4-deep.

#define EPS 1e-6f

static constexpr long long NTOT = 32LL * 8 * 3 * 256 * 256;  // 50,331,648
static constexpr int RPS    = 32;                  // rows per strip
static constexpr int STRIPS = 768 * (256 / RPS);   // 6144
static constexpr int WPB    = 4;                   // waves per block
static constexpr int BLOCKS = STRIPS / WPB;        // 1536

__global__ void __launch_bounds__(256)
tv_strip_kernel(const float* __restrict__ x, double* __restrict__ partial) {
    const int wid   = threadIdx.x >> 6;
    const int lane  = threadIdx.x & 63;
    const int strip = blockIdx.x * WPB + wid;        // 0 .. 6143
    const int img   = strip >> 3;                    // 8 strips per image
    const int r0    = (strip & 7) << 5;              // first row of strip

    const float* p = x + (size_t)img * 65536 + (size_t)r0 * 256 + lane * 4;

    float acc = 0.0f;
    float4 a = *reinterpret_cast<const float4*>(p);

    // rows r0+1 .. r0+31 are always inside the image: branch-free body.
    #pragma unroll 4
    for (int k = 1; k < RPS; ++k) {
        const float4 b = *reinterpret_cast<const float4*>(p + k * 256);
        // horizontal diffs for row r0+k-1
        acc += fabsf(a.y - a.x + EPS);
        acc += fabsf(a.z - a.y + EPS);
        acc += fabsf(a.w - a.z + EPS);
        const float nx = __shfl_down(a.x, 1, 64);    // neighbor float4's .x
        if (lane < 63) acc += fabsf(nx - a.w + EPS); // lane 63 = row end
        // vertical diffs row r0+k-1 -> r0+k
        acc += fabsf(b.x - a.x + EPS);
        acc += fabsf(b.y - a.y + EPS);
        acc += fabsf(b.z - a.z + EPS);
        acc += fabsf(b.w - a.w + EPS);
        a = b;
    }

    // epilogue: last row of the strip (r0+31)
    acc += fabsf(a.y - a.x + EPS);
    acc += fabsf(a.z - a.y + EPS);
    acc += fabsf(a.w - a.z + EPS);
    {
        const float nx = __shfl_down(a.x, 1, 64);
        if (lane < 63) acc += fabsf(nx - a.w + EPS);
    }
    // vertical diff into the next strip's first row, unless this is the
    // image's last strip (wave-uniform branch, executed once).
    if (r0 < 256 - RPS) {
        const float4 b = *reinterpret_cast<const float4*>(p + RPS * 256);
        acc += fabsf(b.x - a.x + EPS);
        acc += fabsf(b.y - a.y + EPS);
        acc += fabsf(b.z - a.z + EPS);
        acc += fabsf(b.w - a.w + EPS);
    }

    // wave reduction
    #pragma unroll
    for (int off = 32; off > 0; off >>= 1)
        acc += __shfl_down(acc, off, 64);

    __shared__ double sdata[WPB];
    if (lane == 0) sdata[wid] = (double)acc;
    __syncthreads();
    if (threadIdx.x == 0)
        partial[blockIdx.x] = sdata[0] + sdata[1] + sdata[2] + sdata[3];
}

__global__ void __launch_bounds__(256)
tv_final_kernel(const double* __restrict__ partial, float* __restrict__ out) {
    double s = 0.0;
    for (int i = threadIdx.x; i < BLOCKS; i += 256)
        s += partial[i];
    #pragma unroll
    for (int off = 32; off > 0; off >>= 1)
        s += __shfl_down(s, off, 64);
    __shared__ double sd[4];
    const int wid  = threadIdx.x >> 6;
    const int lane = threadIdx.x & 63;
    if (lane == 0) sd[wid] = s;
    __syncthreads();
    if (threadIdx.x == 0)
        out[0] = (float)((sd[0] + sd[1] + sd[2] + sd[3]) / (double)NTOT);
}

extern "C" void kernel_launch(void* const* d_in, const int* in_sizes, int n_in,
                              void* d_out, int out_size, void* d_ws, size_t ws_size,
                              hipStream_t stream) {
    const float* x   = (const float*)d_in[0];
    float*       out = (float*)d_out;
    double*      ws  = (double*)d_ws;   // BLOCKS doubles = 12 KB of scratch

    tv_strip_kernel<<<BLOCKS, 256, 0, stream>>>(x, ws);
    tv_final_kernel<<<1, 256, 0, stream>>>(ws, out);
}